// Round 11
// baseline (159.424 us; speedup 1.0000x reference)
//
#include <hip/hip_runtime.h>
#include <hip/hip_bf16.h>

#define B_ 16
#define T_ 1024
#define MEL_ 80
#define C_ 512
#define NL_ 6
#define NS_ 32
#define HBSTR 1096   // per-channel LDS h-buffer stride (halves): 32 pad + 1024 + 40 tail

typedef _Float16 f16x8 __attribute__((ext_vector_type(8)));
typedef float f32x4 __attribute__((ext_vector_type(4)));

// ---------------------------------------------------------------- wave reduce
__device__ __forceinline__ float wred(float v) {
#pragma unroll
    for (int m = 32; m >= 1; m >>= 1) v += __shfl_xor(v, m, 64);
    return v;
}

__device__ __forceinline__ unsigned int pkh(float a, float b) {
    typedef __fp16 h2 __attribute__((ext_vector_type(2)));
    h2 r = __builtin_amdgcn_cvt_pkrtz(a, b);   // builtin returns __fp16x2
    return __builtin_bit_cast(unsigned int, r);
}
__device__ __forceinline__ float h2f(unsigned short u) {
    return (float)__builtin_bit_cast(_Float16, u);
}

// ---------------------------------------------------------------- fused projection + tap fragments
// Blocks 0..511: MFMA in_proj (R10-verified). Blocks 512..1279: tap fragment
// build (R9-verified). Merged to kill one launch gap; bodies are block-uniform.
__global__ __launch_bounds__(256) void proj_taps(const float* __restrict__ mel,
                                                 const float* __restrict__ w_in,
                                                 const float* __restrict__ b_in,
                                                 const float* __restrict__ freq,
                                                 const float* __restrict__ logA,
                                                 const float* __restrict__ Cp,
                                                 const float* __restrict__ Dp,
                                                 float* __restrict__ h0T,
                                                 unsigned short* __restrict__ AH,
                                                 unsigned short* __restrict__ AL) {
    __shared__ float KT[4][32];
    if (blockIdx.x < 512) {
        // ---- in_proj: h0 = mel @ w_in + bias + freq -> h0T[b][c][t] (f32) ----
        // wave = (16-row m-tile, 256-col c-half). D mapping (R9-verified):
        // col=lane&15 -> c, row=4hh+r -> t; one float4 store covers 16 full
        // 64B lines of h0T. K=80 padded to 96 (chunk2 zeroed for hh>=2).
        const int wid = blockIdx.x * 4 + (threadIdx.x >> 6);   // 0..2047
        const int lane = threadIdx.x & 63;
        const int mtile = wid >> 1;
        const int chalf = wid & 1;
        const int rbase = mtile * 16;
        const int b = rbase >> 10;
        const int tloc = rbase & 1023;
        const int n = lane & 15, hh = lane >> 4;

        f16x8 Am[3];
#pragma unroll
        for (int ch = 0; ch < 3; ++ch) {
            f16x8 a = {0, 0, 0, 0, 0, 0, 0, 0};
            if (ch < 2 || hh < 2) {
                const float* mp = mel + (size_t)(rbase + n) * MEL_ + 32 * ch + 8 * hh;
                float4 m0 = *(const float4*)(mp);
                float4 m1 = *(const float4*)(mp + 4);
                a[0] = (_Float16)m0.x; a[1] = (_Float16)m0.y;
                a[2] = (_Float16)m0.z; a[3] = (_Float16)m0.w;
                a[4] = (_Float16)m1.x; a[5] = (_Float16)m1.y;
                a[6] = (_Float16)m1.z; a[7] = (_Float16)m1.w;
            }
            Am[ch] = a;
        }
#pragma unroll 4
        for (int it = 0; it < 16; ++it) {
            const int ct = chalf * 256 + it * 16;
            const int c = ct + n;
            f16x8 Bw[3];
#pragma unroll
            for (int ch = 0; ch < 3; ++ch) {
                f16x8 w = {0, 0, 0, 0, 0, 0, 0, 0};
                if (ch < 2 || hh < 2) {
#pragma unroll
                    for (int e = 0; e < 8; ++e)
                        w[e] = (_Float16)w_in[(size_t)(32 * ch + 8 * hh + e) * C_ + c];
                }
                Bw[ch] = w;
            }
            f32x4 d = {0.f, 0.f, 0.f, 0.f};
            d = __builtin_amdgcn_mfma_f32_16x16x32_f16(Am[0], Bw[0], d, 0, 0, 0);
            d = __builtin_amdgcn_mfma_f32_16x16x32_f16(Am[1], Bw[1], d, 0, 0, 0);
            d = __builtin_amdgcn_mfma_f32_16x16x32_f16(Am[2], Bw[2], d, 0, 0, 0);
            float bias = b_in[c];
            float4 v;
#pragma unroll
            for (int r = 0; r < 4; ++r) {
                int t = tloc + 4 * hh + r;
                int fr = t < 513 ? t : 512;
                ((float*)&v)[r] = d[r] + bias + freq[(size_t)fr * C_ + c];
            }
            *(float4*)(h0T + ((size_t)b * C_ + c) * T_ + tloc + 4 * hh) = v;
        }
    } else {
        // ---- tap fragments: A_hi[m][k]=K[32+m-k], A_lo[m][k]=K[m-k] ----
        const int gid0 = (blockIdx.x - 512) * 4;    // gid = l*C + c
        const int tid = threadIdx.x;
        if (tid < 128) {
            int gl = tid >> 5, tau = tid & 31;
            int gid = gid0 + gl;
            const float* la = logA + (size_t)gid * NS_;
            const float* cp = Cp + (size_t)gid * NS_;
            float s = 0.f;
            float t = (float)tau;
#pragma unroll 8
            for (int nn = 0; nn < NS_; ++nn)
                s += cp[nn] * expf(-expf(la[nn]) * t);
            if (tau == 0) s += Dp[gid];
            KT[gl][tau] = s;
        }
        __syncthreads();
        const int wv = tid >> 6, lane = tid & 63;
        const int gid = gid0 + wv;
        float kv = KT[wv][lane & 31];
        const int m = lane & 15, hh = lane >> 4;
        f16x8 vh, vl;
#pragma unroll
        for (int e = 0; e < 8; ++e) {
            int th = 32 + m - 8 * hh - e;
            int tl = m - 8 * hh - e;
            float a = __shfl(kv, th & 31, 64);
            float bq = __shfl(kv, tl & 31, 64);
            vh[e] = (th >= 0 && th < 32) ? (_Float16)a : (_Float16)0.f;
            vl[e] = (tl >= 0 && tl < 32) ? (_Float16)bq : (_Float16)0.f;
        }
        *(f16x8*)(AH + (size_t)gid * 512 + lane * 8) = vh;
        *(f16x8*)(AL + (size_t)gid * 512 + lane * 8) = vl;
    }
}

// ---------------------------------------------------------------- fused 6-layer S4D stack (MFMA, t-split)
// R10 theory: conv was latency-bound (serial per-wave layer chain, ~16 waves/CU).
// TLP x2: TWO WAVES PER CHANNEL (t<512 / t>=512), 16-wave blocks, double-buffered
// h (35KB LDS), ONE barrier per layer (dbuf removes read/write hazard). Per wave
// per layer: 4 ds_read_b128, 4 mfma_f32_16x16x32_f16, 8-value gelu, 2 ds_write.
// Toeplitz split (R7-verified): D[m][n] = Ahi x h[256q+16n-32+k] + Alo x h[256q+16n+k].
__global__ __launch_bounds__(1024) void conv_stack(const float* __restrict__ h0T,
                                                   float* __restrict__ hfin,
                                                   const unsigned short* __restrict__ AH,
                                                   const unsigned short* __restrict__ AL,
                                                   float* __restrict__ hm) {
    __shared__ unsigned short HB[2][8 * HBSTR];   // 35,072 B
    __shared__ float HS[16];
    const int b = blockIdx.y;
    const int gx = blockIdx.x;                       // 64 groups
    const int c0 = 8 * (((gx & 7) << 3) | (gx >> 3)); // XCD i -> channels 64i..64i+63
    const int tid = threadIdx.x;
    const int lane = tid & 63;
    const int wv = tid >> 6;                         // 0..15
    const int ch = wv >> 1;                          // channel slot 0..7
    const int half = wv & 1;                         // t-half
    const int c = __builtin_amdgcn_readfirstlane(c0 + ch);

    unsigned short* hb0 = &HB[0][ch * HBSTR];
    unsigned short* hb1 = &HB[1][ch * HBSTR];

    // pads (both buffers): front [0,32) = h[t<0]=0; tail [1056,1096) anti-NaN
    if (half == 0 && lane < 32) { hb0[lane] = 0; hb1[lane] = 0; }
    if (half == 1 && lane < 40) { hb0[1056 + lane] = 0; hb1[1056 + lane] = 0; }

    {   // entry: lane loads its 8 t (f32), packs f16 into buf0
        const float* src = h0T + ((size_t)b * C_ + c) * T_ + 512 * half + 8 * lane;
        float4 e0 = *(const float4*)(src);
        float4 e1 = *(const float4*)(src + 4);
        uint4 p;
        p.x = pkh(e0.x, e0.y); p.y = pkh(e0.z, e0.w);
        p.z = pkh(e1.x, e1.y); p.w = pkh(e1.z, e1.w);
        *(uint4*)(&hb0[32 + 512 * half + 8 * lane]) = p;
    }
    __syncthreads();

    const int n = lane & 15, hh = lane >> 4;
    const int boff = 16 * n + 8 * hh;
    const int woff = 32 + 16 * n + 4 * hh;

    f16x8 Ah = *(const f16x8*)(AH + (size_t)c * 512 + lane * 8);   // l=0
    f16x8 Al = *(const f16x8*)(AL + (size_t)c * 512 + lane * 8);

    float hsum = 0.f;
    for (int l = 0; l < NL_; ++l) {
        const unsigned short* cur = (l & 1) ? hb1 : hb0;
        unsigned short* nxt = (l & 1) ? hb0 : hb1;
        const int ln = (l + 1 < NL_) ? l + 1 : 0;    // dummy prefetch on last
        f16x8 nAh = *(const f16x8*)(AH + ((size_t)ln * C_ + c) * 512 + lane * 8);
        f16x8 nAl = *(const f16x8*)(AL + ((size_t)ln * C_ + c) * 512 + lane * 8);

        f32x4 d[2];
#pragma unroll
        for (int qq = 0; qq < 2; ++qq) {
            const int q = 2 * half + qq;
            const unsigned short* base = cur + 256 * q + boff;
            f16x8 Bh = *(const f16x8*)(base);          // h[256q+16n-32+k]
            f16x8 Bl = *(const f16x8*)(base + 32);     // h[256q+16n+k]
            f32x4 z = {0.f, 0.f, 0.f, 0.f};
            d[qq] = __builtin_amdgcn_mfma_f32_16x16x32_f16(Ah, Bh, z, 0, 0, 0);
            d[qq] = __builtin_amdgcn_mfma_f32_16x16x32_f16(Al, Bl, d[qq], 0, 0, 0);
        }
        // gelu (f32) + pack to the OTHER buffer
#pragma unroll
        for (int qq = 0; qq < 2; ++qq) {
            const int q = 2 * half + qq;
            float g[4];
#pragma unroll
            for (int r = 0; r < 4; ++r) {
                float y = d[qq][r];
                float u2 = y * (y * y * 0.07135481627f + 1.59576912161f);
                float rr = __builtin_amdgcn_rcpf(__expf(u2) + 1.f);
                g[r] = y - y * rr;
            }
            if (l == NL_ - 1) hsum += g[0] + g[1] + g[2] + g[3];
            uint2 pw;
            pw.x = pkh(g[0], g[1]);
            pw.y = pkh(g[2], g[3]);
            *(uint2*)(&nxt[woff + 256 * q]) = pw;      // t = 256q+16n+4hh+r
        }
        Ah = nAh; Al = nAl;
        __syncthreads();
    }

    // time mean per channel: combine the two half-wave sums
    {
        float s = wred(hsum);
        if (lane == 0) HS[wv] = s;
    }
    __syncthreads();
    if (tid < 8)
        hm[(size_t)b * C_ + c0 + tid] = (HS[2 * tid] + HS[2 * tid + 1]) * (1.f / T_);

    // exit: cross-wave LDS transpose (buf0 holds final h) -> hfin[b][t][C] f32
    {
        float* dst = hfin + (size_t)b * T_ * C_ + c0;
#pragma unroll
        for (int it = 0; it < 2; ++it) {
            int idx = it * 1024 + tid;                // 0..2047
            int t = idx >> 1, u = idx & 1;
            float4 v;
            v.x = h2f(HB[0][(4 * u + 0) * HBSTR + 32 + t]);
            v.y = h2f(HB[0][(4 * u + 1) * HBSTR + 32 + t]);
            v.z = h2f(HB[0][(4 * u + 2) * HBSTR + 32 + t]);
            v.w = h2f(HB[0][(4 * u + 3) * HBSTR + 32 + t]);
            *(float4*)(dst + (size_t)t * C_ + 4 * u) = v;
        }
    }
}

// ---------------------------------------------------------------- per-row heads
// Row-major single-pass version: params hoisted into registers once per wave;
// each wave processes 4 rows.
__global__ __launch_bounds__(256) void heads_rows(const float* __restrict__ h,
                                                  const float* __restrict__ ln_g,
                                                  const float* __restrict__ ln_b,
                                                  const float* __restrict__ w5,
                                                  const float* __restrict__ b5,
                                                  float* __restrict__ out) {
    int wv = threadIdx.x >> 6, lane = threadIdx.x & 63;
    int r0 = blockIdx.x * 16 + wv * 4;
    float g[3][8], bb[3][8], ww[3][8];
#pragma unroll
    for (int o = 0; o < 3; ++o) {
        const float* gp = ln_g + o * C_ + lane * 8;
        const float* bp = ln_b + o * C_ + lane * 8;
        const float* wp = w5 + o * C_ + lane * 8;
        float4 a, bq;
        a = *(const float4*)(gp); bq = *(const float4*)(gp + 4);
        g[o][0]=a.x; g[o][1]=a.y; g[o][2]=a.z; g[o][3]=a.w;
        g[o][4]=bq.x; g[o][5]=bq.y; g[o][6]=bq.z; g[o][7]=bq.w;
        a = *(const float4*)(bp); bq = *(const float4*)(bp + 4);
        bb[o][0]=a.x; bb[o][1]=a.y; bb[o][2]=a.z; bb[o][3]=a.w;
        bb[o][4]=bq.x; bb[o][5]=bq.y; bb[o][6]=bq.z; bb[o][7]=bq.w;
        a = *(const float4*)(wp); bq = *(const float4*)(wp + 4);
        ww[o][0]=a.x; ww[o][1]=a.y; ww[o][2]=a.z; ww[o][3]=a.w;
        ww[o][4]=bq.x; ww[o][5]=bq.y; ww[o][6]=bq.z; ww[o][7]=bq.w;
    }
    float b5r[3] = {b5[0], b5[1], b5[2]};
#pragma unroll
    for (int rr = 0; rr < 4; ++rr) {
        const int r = r0 + rr;
        const float* row = h + (size_t)r * C_ + lane * 8;
        float x[8];
        {
            float4 xa = *(const float4*)(row);
            float4 xb = *(const float4*)(row + 4);
            x[0]=xa.x; x[1]=xa.y; x[2]=xa.z; x[3]=xa.w;
            x[4]=xb.x; x[5]=xb.y; x[6]=xb.z; x[7]=xb.w;
        }
        float s = 0.f;
#pragma unroll
        for (int i = 0; i < 8; ++i) s += x[i];
        float mu = wred(s) * (1.f / C_);
        float v = 0.f;
#pragma unroll
        for (int i = 0; i < 8; ++i) { float d = x[i] - mu; v += d * d; }
        float rstd = rsqrtf(wred(v) * (1.f / C_) + 1e-5f);
#pragma unroll
        for (int o = 0; o < 3; ++o) {
            float acc = 0.f;
#pragma unroll
            for (int i = 0; i < 8; ++i) {
                float xn = (x[i] - mu) * rstd * g[o][i] + bb[o][i];
                acc += xn * ww[o][i];
            }
            acc = wred(acc);
            if (lane == 0) out[o * (B_ * T_) + r] = acc + b5r[o];
        }
    }
}

// ---------------------------------------------------------------- utterance heads
__global__ __launch_bounds__(64) void heads_utt(const float* __restrict__ hm,
                                                const float* __restrict__ ln_g,
                                                const float* __restrict__ ln_b,
                                                const float* __restrict__ w5,
                                                const float* __restrict__ b5,
                                                const float* __restrict__ wm,
                                                const float* __restrict__ bm,
                                                float* __restrict__ out) {
    int b = blockIdx.x;
    int lane = threadIdx.x;
    const float* row = hm + (size_t)b * C_;
    float x[8];
#pragma unroll
    for (int i = 0; i < 8; ++i) x[i] = row[lane + 64 * i];
    float s = 0.f;
#pragma unroll
    for (int i = 0; i < 8; ++i) s += x[i];
    float mu = wred(s) * (1.f / C_);
    float v = 0.f;
#pragma unroll
    for (int i = 0; i < 8; ++i) { float d = x[i] - mu; v += d * d; }
    float rstd = rsqrtf(wred(v) * (1.f / C_) + 1e-5f);

    const int OUT_SR = 3 * B_ * T_;              // 49152
    const int OUT_PD = OUT_SR + B_;              // 49168
    const int OUT_MF = OUT_PD + B_;              // 49184
#pragma unroll
    for (int o = 3; o <= 4; ++o) {
        float acc = 0.f;
#pragma unroll
        for (int i = 0; i < 8; ++i) {
            int cc = lane + 64 * i;
            float xn = (x[i] - mu) * rstd * ln_g[o * C_ + cc] + ln_b[o * C_ + cc];
            acc += xn * w5[o * C_ + cc];
        }
        acc = wred(acc);
        if (lane == 0) out[(o == 3 ? OUT_SR : OUT_PD) + b] = acc + b5[o];
    }
    float mf[13];
#pragma unroll
    for (int j = 0; j < 13; ++j) mf[j] = 0.f;
#pragma unroll
    for (int i = 0; i < 8; ++i) {
        int cc = lane + 64 * i;
        float xn = (x[i] - mu) * rstd * ln_g[5 * C_ + cc] + ln_b[5 * C_ + cc];
#pragma unroll
        for (int j = 0; j < 13; ++j) mf[j] += xn * wm[cc * 13 + j];
    }
#pragma unroll
    for (int j = 0; j < 13; ++j) {
        float m = wred(mf[j]);
        if (lane == 0) out[OUT_MF + b * 13 + j] = m + bm[j];
    }
}

// ---------------------------------------------------------------- launch
extern "C" void kernel_launch(void* const* d_in, const int* in_sizes, int n_in,
                              void* d_out, int out_size, void* d_ws, size_t ws_size,
                              hipStream_t stream) {
    const float* mel   = (const float*)d_in[0];
    const float* w_in  = (const float*)d_in[1];
    const float* b_in  = (const float*)d_in[2];
    const float* freq  = (const float*)d_in[3];
    const float* logA  = (const float*)d_in[4];
    const float* s4C   = (const float*)d_in[5];
    const float* s4D   = (const float*)d_in[6];
    const float* ln_g  = (const float*)d_in[7];
    const float* ln_b  = (const float*)d_in[8];
    const float* w5    = (const float*)d_in[9];
    const float* b5    = (const float*)d_in[10];
    const float* wm    = (const float*)d_in[11];
    const float* bm    = (const float*)d_in[12];
    float* out = (float*)d_out;

    char* ws = (char*)d_ws;
    const size_t HBYTES = (size_t)B_ * T_ * C_ * sizeof(float);   // 33.55 MB
    float* hA = (float*)ws;                                       // h0T  [b][c][t]
    float* hB = (float*)(ws + HBYTES);                            // hfin [b][t][C]
    float* hm = (float*)(ws + 2 * HBYTES);                        // 16*512 f32
    unsigned short* AH = (unsigned short*)(ws + 2 * HBYTES +
                                           (size_t)B_ * C_ * sizeof(float));
    unsigned short* AL = AH + (size_t)NL_ * C_ * 512;             // 3.1 MB each

    proj_taps<<<1280, 256, 0, stream>>>(mel, w_in, b_in, freq,
                                        logA, s4C, s4D, hA, AH, AL);
    conv_stack<<<dim3(C_ / 8, B_), 1024, 0, stream>>>(hA, hB, AH, AL, hm);
    heads_rows<<<(B_ * T_) / 16, 256, 0, stream>>>(hB, ln_g, ln_b, w5, b5, out);
    heads_utt<<<B_, 64, 0, stream>>>(hm, ln_g, ln_b, w5, b5, wm, bm, out);
}

// Round 12
// 149.267 us; speedup vs baseline: 1.0681x; 1.0681x over previous
//
#include <hip/hip_runtime.h>
#include <hip/hip_bf16.h>

#define B_ 16
#define T_ 1024
#define MEL_ 80
#define C_ 512
#define NL_ 6
#define NS_ 32
#define KSTR 32      // tap storage stride; builder fills 32, MFMA path uses ALL 32
#define HBSTR 1096   // per-wave LDS h-buffer stride (halves): 32 pad + 1024 + 40 tail

typedef float v2f __attribute__((ext_vector_type(2)));
typedef _Float16 f16x8 __attribute__((ext_vector_type(8)));
typedef float f32x4 __attribute__((ext_vector_type(4)));

// ---------------------------------------------------------------- wave reduce
__device__ __forceinline__ float wred(float v) {
#pragma unroll
    for (int m = 32; m >= 1; m >>= 1) v += __shfl_xor(v, m, 64);
    return v;
}

__device__ __forceinline__ unsigned int pkh(float a, float b) {
    typedef __fp16 h2 __attribute__((ext_vector_type(2)));
    h2 r = __builtin_amdgcn_cvt_pkrtz(a, b);   // builtin returns __fp16x2
    return __builtin_bit_cast(unsigned int, r);
}

// ---------------------------------------------------------------- input proj (+ fused tap build)
// Main: h0T[b][c][t] (transposed) for conv's coalesced per-wave entry.
// Tail: blocks with by<6 also build layer-by's taps (64 blk x 256 thr = 512c x 32tau).
// Kt[(l*C + c)*KSTR + tau]; Kt[..][0] absorbs D.
__global__ __launch_bounds__(256) void in_proj(const float* __restrict__ mel,
                                               const float* __restrict__ w_in,
                                               const float* __restrict__ b_in,
                                               const float* __restrict__ freq,
                                               const float* __restrict__ logA,
                                               const float* __restrict__ Cp,
                                               const float* __restrict__ Dp,
                                               float* __restrict__ h0T,
                                               float* __restrict__ Kt) {
    __shared__ float lds[C_ * 20];      // 40,960 B
    const int b = blockIdx.y;
    const int t0 = blockIdx.x * 16;
    const int tid = threadIdx.x;
    const float* melb = mel + ((size_t)b * T_ + t0) * MEL_;

    v2f acc[16];
#pragma unroll
    for (int t = 0; t < 16; ++t) acc[t] = (v2f){0.f, 0.f};
#pragma unroll 4
    for (int k = 0; k < MEL_; ++k) {
        v2f w01 = {w_in[(size_t)k * C_ + tid], w_in[(size_t)k * C_ + tid + 256]};
#pragma unroll
        for (int t = 0; t < 16; ++t) {
            float mv = melb[t * MEL_ + k];       // wave-uniform s_load
            acc[t] = __builtin_elementwise_fma((v2f){mv, mv}, w01, acc[t]);
        }
    }
    float bias0 = b_in[tid], bias1 = b_in[tid + 256];
#pragma unroll
    for (int t = 0; t < 16; ++t) {
        int tt = t0 + t;
        int fr = tt < 513 ? tt : 512;
        lds[tid * 20 + t] = acc[t][0] + bias0 + freq[(size_t)fr * C_ + tid];
        lds[(tid + 256) * 20 + t] = acc[t][1] + bias1 + freq[(size_t)fr * C_ + tid + 256];
    }
    __syncthreads();
    const int tq = tid & 3;
#pragma unroll
    for (int rep = 0; rep < 8; ++rep) {
        int c = 64 * rep + (tid >> 2);
        float4 v = *(const float4*)(&lds[c * 20 + 4 * tq]);
        *(float4*)(h0T + ((size_t)b * C_ + c) * T_ + t0 + 4 * tq) = v;
    }

    // fused tap build: 6*64 blocks cover (l=by, idx = bx*256+tid -> c,tau)
    if (b < NL_) {
        int idx = blockIdx.x * 256 + tid;          // 0..16383
        int tau = idx & (KSTR - 1);
        int c = idx >> 5;
        const float* la = logA + ((size_t)b * C_ + c) * NS_;
        const float* cp = Cp + ((size_t)b * C_ + c) * NS_;
        float s = 0.f;
        float t = (float)tau;
#pragma unroll 8
        for (int n = 0; n < NS_; ++n)
            s += cp[n] * expf(-expf(la[n]) * t);
        if (tau == 0) s += Dp[b * C_ + c];
        Kt[((size_t)b * C_ + c) * KSTR + tau] = s;
    }
}

// ---------------------------------------------------------------- tap fragments
// Build per-(l,c) MFMA A-operand fragments (f16) from Kt:
//   A_hi[m][k] = K[32+m-k], A_lo[m][k] = K[m-k], zero out of [0,32).
// Fragment layout (v_mfma_f32_16x16x32_f16 A): lane holds A[lane&15][8*(lane>>4)+e].
// One wave per (l,c); stores 8 halves (16B) per lane per matrix.
__global__ __launch_bounds__(256) void tap_frags(const float* __restrict__ Kt,
                                                 unsigned short* __restrict__ AH,
                                                 unsigned short* __restrict__ AL) {
    const int gid = blockIdx.x * 4 + (threadIdx.x >> 6);   // l*512 + c
    const int lane = threadIdx.x & 63;
    const float* kp = Kt + (size_t)gid * KSTR;
    float kv = kp[lane & 31];                // lanes 0..31 hold taps 0..31
    const int m = lane & 15, hh = lane >> 4;
    f16x8 vh, vl;
#pragma unroll
    for (int e = 0; e < 8; ++e) {
        int th = 32 + m - 8 * hh - e;
        int tl = m - 8 * hh - e;
        float a = __shfl(kv, th & 31, 64);
        float bq = __shfl(kv, tl & 31, 64);
        vh[e] = (th >= 0 && th < 32) ? (_Float16)a : (_Float16)0.f;
        vl[e] = (tl >= 0 && tl < 32) ? (_Float16)bq : (_Float16)0.f;
    }
    *(f16x8*)(AH + (size_t)gid * 512 + lane * 8) = vh;
    *(f16x8*)(AL + (size_t)gid * 512 + lane * 8) = vl;
}

// ---------------------------------------------------------------- fused 6-layer S4D stack (MFMA)
// ONE CHANNEL PER WAVE; h lives in a wave-private LDS f16 buffer (no barriers
// in the layer loop). Per layer: 2 global dwordx4 (A frags), 8 ds_read_b128
// (B windows), 8 mfma_f32_16x16x32_f16, f32 gelu, 4 ds_write_b64.
// Toeplitz split: D[m][n] = sum_k Ahi[m][k] h[256q+16n-32+k]
//                          + sum_k Alo[m][k] h[256q+16n+k]  = y[256q+16n+m],
// covering taps 0..31 exactly once. This structure measured 146.3 us total (R7,
// session best); R8-R11 variants (f16 IO, fusion, t-split) all regressed.
__global__ __launch_bounds__(512) void conv_stack(const float* __restrict__ h0T,
                                                  float* __restrict__ hfin,
                                                  const unsigned short* __restrict__ AH,
                                                  const unsigned short* __restrict__ AL,
                                                  float* __restrict__ hm) {
    __shared__ unsigned short HB[8 * HBSTR];   // 17,536 B
    const int b = blockIdx.y;
    const int gx = blockIdx.x;                       // 64 groups
    const int c0 = 8 * (((gx & 7) << 3) | (gx >> 3)); // XCD i -> channels 64i..64i+63
    const int tid = threadIdx.x;
    const int lane = tid & 63;
    const int wv = tid >> 6;
    const int c = __builtin_amdgcn_readfirstlane(c0 + wv);   // wave-uniform channel
    unsigned short* hb = &HB[wv * HBSTR];

    // zero pads: [0,32) front (h[t<0]=0), [1056,1096) tail (avoid NaN*0 in MFMA)
    if (lane < 32) hb[lane] = 0;
    if (lane < 40) hb[1056 + lane] = 0;

    {   // entry: lane L loads t = 16L..16L+15 (f32), packs f16 into hb[32+t]
        const float* srcT = h0T + ((size_t)b * C_ + c) * T_ + 16 * lane;
        float4 e0 = *(const float4*)(srcT);
        float4 e1 = *(const float4*)(srcT + 4);
        float4 e2 = *(const float4*)(srcT + 8);
        float4 e3 = *(const float4*)(srcT + 12);
        uint4 p0, p1;
        p0.x = pkh(e0.x, e0.y); p0.y = pkh(e0.z, e0.w);
        p0.z = pkh(e1.x, e1.y); p0.w = pkh(e1.z, e1.w);
        p1.x = pkh(e2.x, e2.y); p1.y = pkh(e2.z, e2.w);
        p1.z = pkh(e3.x, e3.y); p1.w = pkh(e3.z, e3.w);
        *(uint4*)(&hb[32 + 16 * lane]) = p0;
        *(uint4*)(&hb[32 + 16 * lane + 8]) = p1;
    }

    const int n = lane & 15, hh = lane >> 4;
    const int boff = 16 * n + 8 * hh;                // q-base added in loop
    const int woff = 32 + 16 * n + 4 * hh;           // layer output write base

    f16x8 Ah = *(const f16x8*)(AH + (size_t)c * 512 + lane * 8);   // l=0
    f16x8 Al = *(const f16x8*)(AL + (size_t)c * 512 + lane * 8);

    float hsum = 0.f;
    for (int l = 0; l < NL_; ++l) {
        const int ln = (l + 1 < NL_) ? l + 1 : 0;    // dummy prefetch on last
        f16x8 nAh = *(const f16x8*)(AH + ((size_t)ln * C_ + c) * 512 + lane * 8);
        f16x8 nAl = *(const f16x8*)(AL + ((size_t)ln * C_ + c) * 512 + lane * 8);

        f32x4 d[4];
#pragma unroll
        for (int q = 0; q < 4; ++q) {
            const unsigned short* base = hb + 256 * q + boff;
            f16x8 Bh = *(const f16x8*)(base);          // h[256q+16n-32+k]
            f16x8 Bl = *(const f16x8*)(base + 32);     // h[256q+16n+k]
            f32x4 z = {0.f, 0.f, 0.f, 0.f};
            d[q] = __builtin_amdgcn_mfma_f32_16x16x32_f16(Ah, Bh, z, 0, 0, 0);
            d[q] = __builtin_amdgcn_mfma_f32_16x16x32_f16(Al, Bl, d[q], 0, 0, 0);
        }
        // gelu (f32) + pack back to f16 h-buffer
#pragma unroll
        for (int q = 0; q < 4; ++q) {
            float g[4];
#pragma unroll
            for (int r = 0; r < 4; ++r) {
                float y = d[q][r];
                float u2 = y * (y * y * 0.07135481627f + 1.59576912161f);
                float rr = __builtin_amdgcn_rcpf(__expf(u2) + 1.f);
                g[r] = y - y * rr;
            }
            if (l == NL_ - 1) hsum += g[0] + g[1] + g[2] + g[3];
            uint2 pw;
            pw.x = pkh(g[0], g[1]);
            pw.y = pkh(g[2], g[3]);
            *(uint2*)(&hb[woff + 256 * q]) = pw;       // t = 256q+16n+4hh+r
        }
        Ah = nAh; Al = nAl;
    }

    // time mean per channel
    {
        float s = wred(hsum);
        if (lane == 0) hm[(size_t)b * C_ + c] = s * (1.f / T_);
    }

    // exit: cross-wave LDS transpose -> hfin[b][t][C] (f32 from f16 buffer)
    __syncthreads();
    {
        float* dst = hfin + (size_t)b * T_ * C_ + c0;
#pragma unroll
        for (int it = 0; it < 4; ++it) {
            int idx = it * 512 + tid;                 // 0..2047
            int t = idx >> 1, u = idx & 1;
            float4 v;
            v.x = (float)__builtin_bit_cast(_Float16, HB[(4 * u + 0) * HBSTR + 32 + t]);
            v.y = (float)__builtin_bit_cast(_Float16, HB[(4 * u + 1) * HBSTR + 32 + t]);
            v.z = (float)__builtin_bit_cast(_Float16, HB[(4 * u + 2) * HBSTR + 32 + t]);
            v.w = (float)__builtin_bit_cast(_Float16, HB[(4 * u + 3) * HBSTR + 32 + t]);
            *(float4*)(dst + (size_t)t * C_ + 4 * u) = v;
        }
    }
}

// ---------------------------------------------------------------- per-row heads
// Row-major single-pass version: params hoisted into registers once per wave;
// each wave processes 4 rows.
__global__ __launch_bounds__(256) void heads_rows(const float* __restrict__ h,
                                                  const float* __restrict__ ln_g,
                                                  const float* __restrict__ ln_b,
                                                  const float* __restrict__ w5,
                                                  const float* __restrict__ b5,
                                                  float* __restrict__ out) {
    int wv = threadIdx.x >> 6, lane = threadIdx.x & 63;
    int r0 = blockIdx.x * 16 + wv * 4;
    float g[3][8], bb[3][8], ww[3][8];
#pragma unroll
    for (int o = 0; o < 3; ++o) {
        const float* gp = ln_g + o * C_ + lane * 8;
        const float* bp = ln_b + o * C_ + lane * 8;
        const float* wp = w5 + o * C_ + lane * 8;
        float4 a, bq;
        a = *(const float4*)(gp); bq = *(const float4*)(gp + 4);
        g[o][0]=a.x; g[o][1]=a.y; g[o][2]=a.z; g[o][3]=a.w;
        g[o][4]=bq.x; g[o][5]=bq.y; g[o][6]=bq.z; g[o][7]=bq.w;
        a = *(const float4*)(bp); bq = *(const float4*)(bp + 4);
        bb[o][0]=a.x; bb[o][1]=a.y; bb[o][2]=a.z; bb[o][3]=a.w;
        bb[o][4]=bq.x; bb[o][5]=bq.y; bb[o][6]=bq.z; bb[o][7]=bq.w;
        a = *(const float4*)(wp); bq = *(const float4*)(wp + 4);
        ww[o][0]=a.x; ww[o][1]=a.y; ww[o][2]=a.z; ww[o][3]=a.w;
        ww[o][4]=bq.x; ww[o][5]=bq.y; ww[o][6]=bq.z; ww[o][7]=bq.w;
    }
    float b5r[3] = {b5[0], b5[1], b5[2]};
#pragma unroll
    for (int rr = 0; rr < 4; ++rr) {
        const int r = r0 + rr;
        const float* row = h + (size_t)r * C_ + lane * 8;
        float x[8];
        {
            float4 xa = *(const float4*)(row);
            float4 xb = *(const float4*)(row + 4);
            x[0]=xa.x; x[1]=xa.y; x[2]=xa.z; x[3]=xa.w;
            x[4]=xb.x; x[5]=xb.y; x[6]=xb.z; x[7]=xb.w;
        }
        float s = 0.f;
#pragma unroll
        for (int i = 0; i < 8; ++i) s += x[i];
        float mu = wred(s) * (1.f / C_);
        float v = 0.f;
#pragma unroll
        for (int i = 0; i < 8; ++i) { float d = x[i] - mu; v += d * d; }
        float rstd = rsqrtf(wred(v) * (1.f / C_) + 1e-5f);
#pragma unroll
        for (int o = 0; o < 3; ++o) {
            float acc = 0.f;
#pragma unroll
            for (int i = 0; i < 8; ++i) {
                float xn = (x[i] - mu) * rstd * g[o][i] + bb[o][i];
                acc += xn * ww[o][i];
            }
            acc = wred(acc);
            if (lane == 0) out[o * (B_ * T_) + r] = acc + b5r[o];
        }
    }
}

// ---------------------------------------------------------------- utterance heads
__global__ __launch_bounds__(64) void heads_utt(const float* __restrict__ hm,
                                                const float* __restrict__ ln_g,
                                                const float* __restrict__ ln_b,
                                                const float* __restrict__ w5,
                                                const float* __restrict__ b5,
                                                const float* __restrict__ wm,
                                                const float* __restrict__ bm,
                                                float* __restrict__ out) {
    int b = blockIdx.x;
    int lane = threadIdx.x;
    const float* row = hm + (size_t)b * C_;
    float x[8];
#pragma unroll
    for (int i = 0; i < 8; ++i) x[i] = row[lane + 64 * i];
    float s = 0.f;
#pragma unroll
    for (int i = 0; i < 8; ++i) s += x[i];
    float mu = wred(s) * (1.f / C_);
    float v = 0.f;
#pragma unroll
    for (int i = 0; i < 8; ++i) { float d = x[i] - mu; v += d * d; }
    float rstd = rsqrtf(wred(v) * (1.f / C_) + 1e-5f);

    const int OUT_SR = 3 * B_ * T_;              // 49152
    const int OUT_PD = OUT_SR + B_;              // 49168
    const int OUT_MF = OUT_PD + B_;              // 49184
#pragma unroll
    for (int o = 3; o <= 4; ++o) {
        float acc = 0.f;
#pragma unroll
        for (int i = 0; i < 8; ++i) {
            int cc = lane + 64 * i;
            float xn = (x[i] - mu) * rstd * ln_g[o * C_ + cc] + ln_b[o * C_ + cc];
            acc += xn * w5[o * C_ + cc];
        }
        acc = wred(acc);
        if (lane == 0) out[(o == 3 ? OUT_SR : OUT_PD) + b] = acc + b5[o];
    }
    float mf[13];
#pragma unroll
    for (int j = 0; j < 13; ++j) mf[j] = 0.f;
#pragma unroll
    for (int i = 0; i < 8; ++i) {
        int cc = lane + 64 * i;
        float xn = (x[i] - mu) * rstd * ln_g[5 * C_ + cc] + ln_b[5 * C_ + cc];
#pragma unroll
        for (int j = 0; j < 13; ++j) mf[j] += xn * wm[cc * 13 + j];
    }
#pragma unroll
    for (int j = 0; j < 13; ++j) {
        float m = wred(mf[j]);
        if (lane == 0) out[OUT_MF + b * 13 + j] = m + bm[j];
    }
}

// ---------------------------------------------------------------- launch
extern "C" void kernel_launch(void* const* d_in, const int* in_sizes, int n_in,
                              void* d_out, int out_size, void* d_ws, size_t ws_size,
                              hipStream_t stream) {
    const float* mel   = (const float*)d_in[0];
    const float* w_in  = (const float*)d_in[1];
    const float* b_in  = (const float*)d_in[2];
    const float* freq  = (const float*)d_in[3];
    const float* logA  = (const float*)d_in[4];
    const float* s4C   = (const float*)d_in[5];
    const float* s4D   = (const float*)d_in[6];
    const float* ln_g  = (const float*)d_in[7];
    const float* ln_b  = (const float*)d_in[8];
    const float* w5    = (const float*)d_in[9];
    const float* b5    = (const float*)d_in[10];
    const float* wm    = (const float*)d_in[11];
    const float* bm    = (const float*)d_in[12];
    float* out = (float*)d_out;

    char* ws = (char*)d_ws;
    const size_t HBYTES = (size_t)B_ * T_ * C_ * sizeof(float);   // 33.55 MB
    float* hA = (float*)ws;                                       // h0T  [b][c][t]
    float* hB = (float*)(ws + HBYTES);                            // hfin [b][t][C]
    float* Kt = (float*)(ws + 2 * HBYTES);                        // 6*512*32 f32
    char*  p  = ws + 2 * HBYTES + (size_t)NL_ * C_ * KSTR * sizeof(float);
    float* hm = (float*)p;                                        // 16*512 f32
    unsigned short* AH = (unsigned short*)(p + (size_t)B_ * C_ * sizeof(float));
    unsigned short* AL = AH + (size_t)NL_ * C_ * 512;             // 3.1 MB each

    in_proj<<<dim3(T_ / 16, B_), 256, 0, stream>>>(mel, w_in, b_in, freq,
                                                   logA, s4C, s4D, hA, Kt);
    tap_frags<<<(NL_ * C_) / 4, 256, 0, stream>>>(Kt, AH, AL);
    conv_stack<<<dim3(C_ / 8, B_), 512, 0, stream>>>(hA, hB, AH, AL, hm);
    heads_rows<<<(B_ * T_) / 16, 256, 0, stream>>>(hB, ln_g, ln_b, w5, b5, out);
    heads_utt<<<B_, 64, 0, stream>>>(hm, ln_g, ln_b, w5, b5, wm, bm, out);
}